// Round 6
// baseline (311.070 us; speedup 1.0000x reference)
//
#include <hip/hip_runtime.h>

// Householder reflection: out[b,:] = z[b,:] - 2*v[b,:]*(v.z)/(v.v)
// B=8192 rows, L=4096 fp32.
// R0/R3/R4 post-mortem: all block-cooperative versions pin at ~2.2-2.45 TB/s
// regardless of occupancy (16-24 waves/CU) because each CU has only ~3.5
// INDEPENDENT row-streams, each stalling in a long serial phase (dep fma
// chain -> 6 dependent shuffles -> __syncthreads vmcnt(0) drain -> LDS
// round-trip). Compiler also defeated explicit prefetch (R4: VGPR=48 < the
// 64 staging regs needed). Fix: WAVE-PER-ROW. 4096 floats = 64/lane; one
// wave owns a row. Reduction = 6 __shfl_xor steps. ZERO LDS, ZERO barriers,
// no cross-wave rendezvous. ~150 VGPR (128 staging + overhead) -> 3 blocks/CU
// = 12 independent desynchronized row-streams per CU; memory-issue gaps fill
// statistically.

#define L_DIM 4096
#define BLOCK 256
#define WPB (BLOCK / 64)                // 4 waves (= rows) per block
#define NF4 (L_DIM / 4 / 64)            // 16 float4 per lane per array

typedef float f4 __attribute__((ext_vector_type(4)));

__global__ __launch_bounds__(BLOCK, 3) void householder_kernel(
    const float* __restrict__ v,
    const float* __restrict__ z,
    float* __restrict__ out,
    int B)
{
    const int wave = threadIdx.x >> 6;
    const int lane = threadIdx.x & 63;
    const int row = blockIdx.x * WPB + wave;
    if (row >= B) return;

    const size_t base = (size_t)row * L_DIM;
    const f4* v4 = (const f4*)(v + base);
    const f4* z4 = (const f4*)(z + base);
    f4* o4 = (f4*)(out + base);

    // Load the whole row into registers: lane + j*64 is coalesced
    // (64 lanes x 16 B = 1 KiB per wave-instruction).
    f4 a[NF4], b[NF4];
    #pragma unroll
    for (int j = 0; j < NF4; ++j) {
        a[j] = v4[lane + j * 64];
        b[j] = z4[lane + j * 64];
    }

    // Dot products with 4-way accumulator ILP (breaks the dependence chain).
    float vz0 = 0.f, vz1 = 0.f, vz2 = 0.f, vz3 = 0.f;
    float vv0 = 0.f, vv1 = 0.f, vv2 = 0.f, vv3 = 0.f;
    #pragma unroll
    for (int j = 0; j < NF4; j += 4) {
        vz0 = fmaf(a[j+0].x, b[j+0].x, vz0); vz0 = fmaf(a[j+0].y, b[j+0].y, vz0);
        vz0 = fmaf(a[j+0].z, b[j+0].z, vz0); vz0 = fmaf(a[j+0].w, b[j+0].w, vz0);
        vv0 = fmaf(a[j+0].x, a[j+0].x, vv0); vv0 = fmaf(a[j+0].y, a[j+0].y, vv0);
        vv0 = fmaf(a[j+0].z, a[j+0].z, vv0); vv0 = fmaf(a[j+0].w, a[j+0].w, vv0);

        vz1 = fmaf(a[j+1].x, b[j+1].x, vz1); vz1 = fmaf(a[j+1].y, b[j+1].y, vz1);
        vz1 = fmaf(a[j+1].z, b[j+1].z, vz1); vz1 = fmaf(a[j+1].w, b[j+1].w, vz1);
        vv1 = fmaf(a[j+1].x, a[j+1].x, vv1); vv1 = fmaf(a[j+1].y, a[j+1].y, vv1);
        vv1 = fmaf(a[j+1].z, a[j+1].z, vv1); vv1 = fmaf(a[j+1].w, a[j+1].w, vv1);

        vz2 = fmaf(a[j+2].x, b[j+2].x, vz2); vz2 = fmaf(a[j+2].y, b[j+2].y, vz2);
        vz2 = fmaf(a[j+2].z, b[j+2].z, vz2); vz2 = fmaf(a[j+2].w, b[j+2].w, vz2);
        vv2 = fmaf(a[j+2].x, a[j+2].x, vv2); vv2 = fmaf(a[j+2].y, a[j+2].y, vv2);
        vv2 = fmaf(a[j+2].z, a[j+2].z, vv2); vv2 = fmaf(a[j+2].w, a[j+2].w, vv2);

        vz3 = fmaf(a[j+3].x, b[j+3].x, vz3); vz3 = fmaf(a[j+3].y, b[j+3].y, vz3);
        vz3 = fmaf(a[j+3].z, b[j+3].z, vz3); vz3 = fmaf(a[j+3].w, b[j+3].w, vz3);
        vv3 = fmaf(a[j+3].x, a[j+3].x, vv3); vv3 = fmaf(a[j+3].y, a[j+3].y, vv3);
        vv3 = fmaf(a[j+3].w, a[j+3].w, vv3); vv3 = fmaf(a[j+3].z, a[j+3].z, vv3);
    }
    float vz = (vz0 + vz1) + (vz2 + vz3);
    float vv = (vv0 + vv1) + (vv2 + vv3);

    // Wave-wide butterfly reduction: all 64 lanes end with the full sums.
    #pragma unroll
    for (int off = 32; off > 0; off >>= 1) {
        vz += __shfl_xor(vz, off, 64);
        vv += __shfl_xor(vv, off, 64);
    }
    const float s = -2.0f * vz / vv;

    // Epilogue from registers; coalesced 1 KiB wave-stores.
    #pragma unroll
    for (int j = 0; j < NF4; ++j) {
        f4 r;
        r.x = fmaf(s, a[j].x, b[j].x);
        r.y = fmaf(s, a[j].y, b[j].y);
        r.z = fmaf(s, a[j].z, b[j].z);
        r.w = fmaf(s, a[j].w, b[j].w);
        o4[lane + j * 64] = r;
    }
}

extern "C" void kernel_launch(void* const* d_in, const int* in_sizes, int n_in,
                              void* d_out, int out_size, void* d_ws, size_t ws_size,
                              hipStream_t stream) {
    const float* v = (const float*)d_in[0];
    const float* z = (const float*)d_in[1];
    float* out = (float*)d_out;
    const int B = in_sizes[0] / L_DIM;            // 8192 rows
    const int grid = (B + WPB - 1) / WPB;         // 2048 blocks, 1 row per wave
    householder_kernel<<<grid, BLOCK, 0, stream>>>(v, z, out, B);
}